// Round 7
// baseline (397.080 us; speedup 1.0000x reference)
//
#include <hip/hip_runtime.h>
#include <hip/hip_cooperative_groups.h>
#include <math.h>

namespace cg = cooperative_groups;

// SimpleSplitFF: sparse expert-choice MoE, fully fused cooperative kernel.
// x:(4,4096,1024) f32, controller:(1024,32), f1:(1024,32,128), bias:(32,128), f2:(32,128,1024)
// perm is one-hot over g per (b,t,e) scaled by softmax-over-g prob -> only 512 routed rows.

#define DM   1024
#define NE   32
#define FE   128
#define T4   4
#define SS   4096
#define NGRP 1024
#define NROW 512                       // route rows r = (b*4+t)*32+e = row16*32+e
#define LP_STRIDE (NROW * NGRP)        // one K-split partial (2 MiB)
#define VP_OFF   524288                // Vp partials: aliases Lp splits 1-2 (dead after route)

struct SM1 { float xT[64 * 132]; float cs[64 * 32]; };              // logits
struct SM2 { float rmx[4]; float rs[4]; int rgm[4]; };              // route
struct SM3 { float xs[16 * 68]; int gS[16]; };                      // up
struct SM4 { float vv[8 * 132]; float hs[8 * 132]; int gS[8]; float pS[8]; }; // down
union SMU { SM1 p1; SM2 p2; SM3 p3; SM4 p4; };

// 512 blocks x 256 threads, 2 blocks/CU co-resident (42 KB LDS), 3 grid syncs.
__global__ __launch_bounds__(256, 2)
void k_fused(const float* __restrict__ x, const float* __restrict__ ctrl,
             const float* __restrict__ f1, const float* __restrict__ bias,
             const float* __restrict__ f2, float* __restrict__ ws,
             float* __restrict__ out)
{
    __shared__ SMU sm;
    cg::grid_group grid = cg::this_grid();
    const int bid = blockIdx.x;
    const int tid = threadIdx.x;

    // ======== Phase 1: partial logits Lp[ks][row][g] + zero out ========
    // r3-proven layout: 128-tok tile, thread 4tok x 4e, staging row=tid>>2
    // (2-way bank aliasing only).
    {
        const int m      = bid >> 2;
        const int ks     = bid & 3;
        const int base_s = m * 128;            // never straddles b (128 | 4096)
        const int b      = base_s >> 12;
        const int g0     = (base_s & 4095) >> 2;

        const int tq = tid & 31;               // token quad (group)
        const int eg = tid >> 5;               // 0..7 -> experts eg*4..+3

        float acc[4][4];
#pragma unroll
        for (int i = 0; i < 4; ++i)
#pragma unroll
            for (int j = 0; j < 4; ++j) acc[i][j] = 0.f;

        const int row0 = tid >> 2;             // staging token row 0..63 (+64)
        const int f4i  = tid & 3;

        for (int kit = 0; kit < 4; ++kit) {
            const int k0 = ks * 256 + kit * 64;
            __syncthreads();
#pragma unroll
            for (int rr = 0; rr < 2; ++rr) {   // stage x transposed: 128 tok x 64 d
                const int row = row0 + rr * 64;
                const float* xp = x + (size_t)(base_s + row) * DM + k0;
#pragma unroll
                for (int cr = 0; cr < 4; ++cr) {
                    const int col = f4i + cr * 4;
                    const float4 v = *(const float4*)(xp + col * 4);
                    const int d = col * 4;
                    sm.p1.xT[(d + 0) * 132 + row] = v.x;
                    sm.p1.xT[(d + 1) * 132 + row] = v.y;
                    sm.p1.xT[(d + 2) * 132 + row] = v.z;
                    sm.p1.xT[(d + 3) * 132 + row] = v.w;
                }
            }
            {   // stage controller chunk 64 x 32
                const float4* cg4 = (const float4*)(ctrl + (size_t)k0 * NE);
                float4* cl = (float4*)sm.p1.cs;
                cl[tid]       = cg4[tid];
                cl[tid + 256] = cg4[tid + 256];
            }
            __syncthreads();
#pragma unroll 8
            for (int d = 0; d < 64; ++d) {
                const float4 xv = *(const float4*)(sm.p1.xT + d * 132 + tq * 4);
                const float4 cv = *(const float4*)(sm.p1.cs + d * 32 + eg * 4);
                const float xa[4] = { xv.x, xv.y, xv.z, xv.w };
                const float ca[4] = { cv.x, cv.y, cv.z, cv.w };
#pragma unroll
                for (int i = 0; i < 4; ++i)
#pragma unroll
                    for (int j = 0; j < 4; ++j) acc[i][j] += xa[i] * ca[j];
            }
        }

        {   // write partial logits (lanes 0..31 -> consecutive g)
            float* Lb = ws + (size_t)ks * LP_STRIDE;
            const int g = g0 + tq;
#pragma unroll
            for (int i = 0; i < 4; ++i)
#pragma unroll
                for (int j = 0; j < 4; ++j) {
                    const int row = (b * T4 + i) * NE + eg * 4 + j;
                    Lb[(size_t)row * NGRP + g] = acc[i][j];
                }
        }

        {   // fused zero of out: rows [base_s + ks*32, +32)
            const float4 z = make_float4(0.f, 0.f, 0.f, 0.f);
            float4* o4 = (float4*)(out + (size_t)(base_s + ks * 32) * DM);
#pragma unroll 4
            for (int i = tid; i < 32 * DM / 4; i += 256) o4[i] = z;
        }
    }

    grid.sync();

    // ======== Phase 2: route, one block per row (256 thr -> full BW) ========
    // Sums 4 K-partials, online softmax+argmax over g.
    // Stores g (int bits) at ws[row*NGRP], p at ws[row*NGRP+1].
    {
        const int r = bid;
        const float* L0 = ws + (size_t)r * NGRP;
        const int g0c = tid * 4;
        const float4 v0 = *(const float4*)(L0 + g0c);
        const float4 v1 = *(const float4*)(L0 + 1 * LP_STRIDE + g0c);
        const float4 v2 = *(const float4*)(L0 + 2 * LP_STRIDE + g0c);
        const float4 v3 = *(const float4*)(L0 + 3 * LP_STRIDE + g0c);
        const float l[4] = { v0.x + v1.x + v2.x + v3.x,
                             v0.y + v1.y + v2.y + v3.y,
                             v0.z + v1.z + v2.z + v3.z,
                             v0.w + v1.w + v2.w + v3.w };
        float mx = -INFINITY, s = 0.f;
        int gm = 0;
#pragma unroll
        for (int j = 0; j < 4; ++j) {
            const float lv = l[j];
            if (lv > mx) { s = s * __expf(mx - lv) + 1.f; mx = lv; gm = g0c + j; }
            else         { s += __expf(lv - mx); }
        }
#pragma unroll
        for (int off = 1; off < 64; off <<= 1) {
            const float m2 = __shfl_xor(mx, off);
            const float s2 = __shfl_xor(s, off);
            const int   g2 = __shfl_xor(gm, off);
            const float mn = fmaxf(mx, m2);
            s  = s * __expf(mx - mn) + s2 * __expf(m2 - mn);
            gm = (m2 > mx) ? g2 : ((m2 == mx && g2 < gm) ? g2 : gm);
            mx = mn;
        }
        __syncthreads();               // LDS handoff from phase 1
        if ((tid & 63) == 0) {
            const int w = tid >> 6;
            sm.p2.rmx[w] = mx; sm.p2.rs[w] = s; sm.p2.rgm[w] = gm;
        }
        __syncthreads();
        if (tid == 0) {
            float M = sm.p2.rmx[0], S = sm.p2.rs[0];
            int   G = sm.p2.rgm[0];
#pragma unroll
            for (int wv = 1; wv < 4; ++wv) {
                const float m2 = sm.p2.rmx[wv], s2 = sm.p2.rs[wv];
                const int   g2 = sm.p2.rgm[wv];
                const float mn = fmaxf(M, m2);
                S = S * __expf(M - mn) + s2 * __expf(m2 - mn);
                G = (m2 > M) ? g2 : ((m2 == M && g2 < G) ? g2 : G);
                M = mn;
            }
            ((int*)ws)[(size_t)r * NGRP] = G;
            ws[(size_t)r * NGRP + 1] = 1.f / S;
        }
    }

    grid.sync();

    // ======== Phase 3: up-projection partials. bid = (dc 16)<<5 | (e 32) ========
    {
        const int e  = bid & 31;
        const int dc = bid >> 5;
        if (tid < 16) {
            const int rr = tid * NE + e;
            sm.p3.gS[tid] = ((const int*)ws)[(size_t)rr * NGRP];
        }
        __syncthreads();
        {   // stage 16 rows x 64 d: one f4/thread
            const int row = tid >> 4;
            const int f4c = tid & 15;
            const int bq = row >> 2, t = row & 3;
            const int sIdx = bq * SS + sm.p3.gS[row] * 4 + t;
            const float4 v = *(const float4*)(x + (size_t)sIdx * DM + dc * 64 + f4c * 4);
            sm.p3.xs[row * 68 + f4c * 4 + 0] = v.x;
            sm.p3.xs[row * 68 + f4c * 4 + 1] = v.y;
            sm.p3.xs[row * 68 + f4c * 4 + 2] = v.z;
            sm.p3.xs[row * 68 + f4c * 4 + 3] = v.w;
        }
        __syncthreads();

        const int f4 = tid & 31;               // 4 f's
        const int rw = tid >> 5;               // rows rw, rw+8
        const float* f1p = f1 + (size_t)(dc * 64) * (NE * FE) + e * FE + f4 * 4;
        const float* x0 = sm.p3.xs + rw * 68;
        const float* x1 = sm.p3.xs + (rw + 8) * 68;

        float a0[4] = {0.f, 0.f, 0.f, 0.f}, a1[4] = {0.f, 0.f, 0.f, 0.f};
#pragma unroll 16
        for (int dl = 0; dl < 64; ++dl) {
            const float4 w4 = *(const float4*)(f1p + (size_t)dl * (NE * FE));
            const float xa = x0[dl], xb = x1[dl];
            a0[0] += xa * w4.x; a0[1] += xa * w4.y; a0[2] += xa * w4.z; a0[3] += xa * w4.w;
            a1[0] += xb * w4.x; a1[1] += xb * w4.y; a1[2] += xb * w4.z; a1[3] += xb * w4.w;
        }

        float* Vp = ws + VP_OFF + (size_t)(dc * 32 + e) * (16 * FE);
        *(float4*)(Vp + rw       * FE + f4 * 4) = make_float4(a0[0], a0[1], a0[2], a0[3]);
        *(float4*)(Vp + (rw + 8) * FE + f4 * 4) = make_float4(a1[0], a1[1], a1[2], a1[3]);
    }

    grid.sync();

    // ======== Phase 4: reduce + group-relu + down-proj + atomic scatter ========
    // bid = (rh 2)<<8 | (dt 8)<<5 | (e 32). Block: 8 rows x 128-d tile.
    {
        const int e  = bid & 31;
        const int dt = (bid >> 5) & 7;
        const int rh = bid >> 8;

        if (tid < 8) {
            const int rr = (rh * 8 + tid) * NE + e;
            sm.p4.gS[tid] = ((const int*)ws)[(size_t)rr * NGRP];
            sm.p4.pS[tid] = ws[(size_t)rr * NGRP + 1];
        }

        {   // reduce 16 K-chunk partials: one f4-output per thread (row*32+f4)
            const float* Vp = ws + VP_OFF;
            const int row = tid >> 5, f4 = tid & 31;
            float4 s = make_float4(0.f, 0.f, 0.f, 0.f);
#pragma unroll
            for (int dc = 0; dc < 16; ++dc) {
                const float4 v = *(const float4*)(Vp + (size_t)(dc * 32 + e) * (16 * FE)
                                                     + (rh * 8 + row) * FE + f4 * 4);
                s.x += v.x; s.y += v.y; s.z += v.z; s.w += v.w;
            }
            *(float4*)(sm.p4.vv + row * 132 + f4 * 4) = s;
        }
        __syncthreads();

        {   // group-coupled relu, p_t folded; quads are local rows {0..3},{4..7}
#pragma unroll
            for (int q = 0; q < 4; ++q) {
                const int idx = tid + q * 256; // row*128 + f
                const int row = idx >> 7, f = idx & 127;
                const int qb = row & ~3;
                float u = bias[e * FE + f];
#pragma unroll
                for (int t2 = 0; t2 < T4; ++t2)
                    if (sm.p4.gS[qb + t2] == sm.p4.gS[row])
                        u += sm.p4.pS[qb + t2] * sm.p4.vv[(qb + t2) * 132 + f];
                sm.p4.hs[row * 132 + f] = sm.p4.pS[row] * fmaxf(u, 0.f);
            }
        }
        __syncthreads();

        const int d4 = tid & 31;               // 4 d's
        const int rw = tid >> 5;               // local row 0..7
        const float* f2p = f2 + (size_t)e * FE * DM + dt * 128 + d4 * 4;
        const float* hp  = sm.p4.hs + rw * 132;

        float a[4] = {0.f, 0.f, 0.f, 0.f};
#pragma unroll 16
        for (int f = 0; f < FE; ++f) {
            const float4 w4 = *(const float4*)(f2p + (size_t)f * DM);
            const float ha = hp[f];
            a[0] += ha * w4.x; a[1] += ha * w4.y; a[2] += ha * w4.z; a[3] += ha * w4.w;
        }

        const int grow = rh * 8 + rw;
        const int bq = grow >> 2, t = grow & 3;
        float* orow = out + ((size_t)(bq * SS + sm.p4.gS[rw] * 4 + t)) * DM + dt * 128 + d4 * 4;
        atomicAdd(orow + 0, a[0]);
        atomicAdd(orow + 1, a[1]);
        atomicAdd(orow + 2, a[2]);
        atomicAdd(orow + 3, a[3]);
    }
}

// ---------------------------------------------------------------------------
extern "C" void kernel_launch(void* const* d_in, const int* in_sizes, int n_in,
                              void* d_out, int out_size, void* d_ws, size_t ws_size,
                              hipStream_t stream)
{
    const float* x    = (const float*)d_in[0];
    const float* ctrl = (const float*)d_in[1];
    const float* f1   = (const float*)d_in[2];
    const float* bias = (const float*)d_in[3];
    const float* f2   = (const float*)d_in[4];
    float* out = (float*)d_out;
    float* ws  = (float*)d_ws;             // 8 MiB (Lp 4 splits; Vp aliases splits 1-2)

    void* args[] = { (void*)&x, (void*)&ctrl, (void*)&f1, (void*)&bias,
                     (void*)&f2, (void*)&ws, (void*)&out };
    hipLaunchCooperativeKernel((const void*)k_fused, dim3(512), dim3(256),
                               args, 0, stream);
}

// Round 8
// 189.895 us; speedup vs baseline: 2.0911x; 2.0911x over previous
//
#include <hip/hip_runtime.h>
#include <math.h>

// SimpleSplitFF: sparse expert-choice MoE.
// x:(4,4096,1024) f32, controller:(1024,32), f1:(1024,32,128), bias:(32,128), f2:(32,128,1024)
// perm is one-hot over g per (b,t,e) scaled by softmax-over-g prob -> only 512 routed rows.
// Pipeline: k_logits (dbuf) -> k_route -> k_up -> k_down.  ~130us harness floor is fixed.

#define DM   1024
#define NE   32
#define FE   128
#define T4   4
#define SS   4096
#define NGRP 1024
#define NROW 512                       // route rows r = (b*4+t)*32+e = row16*32+e
#define LP_STRIDE (NROW * NGRP)        // one K-split partial (2 MiB)
#define VP_OFF   524288                // Vp partials: aliases Lp splits 1-2 (dead after route)

// ---------------------------------------------------------------------------
// K1: partial logits Lp[ks][row][g] + fused zeroing of d_out.
// grid (128,4) = 512 blocks x 256 thr. Thread tile 4tok x 4e.
// LDS DOUBLE-BUFFERED 32-d kits (8 kits): loads for kit+1 issued before
// compute of kit, stored to the other buffer after -> latency hidden,
// one barrier per kit. 42 KB LDS -> 3 blocks/CU co-resident.
// ---------------------------------------------------------------------------
__global__ __launch_bounds__(256, 3)
void k_logits(const float* __restrict__ x, const float* __restrict__ ctrl,
              float* __restrict__ Lp, float* __restrict__ out)
{
    const int m      = blockIdx.x;
    const int ks     = blockIdx.y;
    const int tid    = threadIdx.x;
    const int base_s = m * 128;                // never straddles b (128 | 4096)
    const int b      = base_s >> 12;
    const int g0     = (base_s & 4095) >> 2;

    __shared__ float xT[2][32 * 132];  // [buf][d][tok], pad 132
    __shared__ float cs[2][32 * 32];   // [buf][d][e]

    const int tq = tid & 31;           // token quad (group)
    const int eg = tid >> 5;           // 0..7 -> experts eg*4..+3

    float acc[4][4];
#pragma unroll
    for (int i = 0; i < 4; ++i)
#pragma unroll
        for (int j = 0; j < 4; ++j) acc[i][j] = 0.f;

    // staging map: row = tid>>1 (0..127), half sq = tid&1 -> f4-cols sq*4..+3
    const int srow = tid >> 1;
    const int sq   = tid & 1;

    float4 px[4];                      // x prefetch: 4 f4 = 16 d
    float4 pc;                        // ctrl prefetch: 1 f4 (256 f4 total)

    const float* xrow = x + (size_t)(base_s + srow) * DM + sq * 16;

    // prologue: load + store kit 0
    {
        const int k0 = ks * 256;
#pragma unroll
        for (int cr = 0; cr < 4; ++cr) px[cr] = *(const float4*)(xrow + k0 + cr * 4);
        pc = ((const float4*)(ctrl + (size_t)k0 * NE))[tid];
#pragma unroll
        for (int cr = 0; cr < 4; ++cr) {
            const int d = (sq * 4 + cr) * 4;
            const float4 v = px[cr];
            xT[0][(d + 0) * 132 + srow] = v.x;
            xT[0][(d + 1) * 132 + srow] = v.y;
            xT[0][(d + 2) * 132 + srow] = v.z;
            xT[0][(d + 3) * 132 + srow] = v.w;
        }
        ((float4*)cs[0])[tid] = pc;
    }
    __syncthreads();

    for (int kit = 0; kit < 8; ++kit) {
        if (kit < 7) {                 // issue next kit's global loads
            const int k0 = ks * 256 + (kit + 1) * 32;
#pragma unroll
            for (int cr = 0; cr < 4; ++cr) px[cr] = *(const float4*)(xrow + k0 + cr * 4);
            pc = ((const float4*)(ctrl + (size_t)k0 * NE))[tid];
        }

        const float* xb = xT[kit & 1];
        const float* cb = cs[kit & 1];
#pragma unroll 8
        for (int d = 0; d < 32; ++d) {
            const float4 xv = *(const float4*)(xb + d * 132 + tq * 4);
            const float4 cv = *(const float4*)(cb + d * 32 + eg * 4);
            const float xa[4] = { xv.x, xv.y, xv.z, xv.w };
            const float ca[4] = { cv.x, cv.y, cv.z, cv.w };
#pragma unroll
            for (int i = 0; i < 4; ++i)
#pragma unroll
                for (int j = 0; j < 4; ++j) acc[i][j] += xa[i] * ca[j];
        }

        if (kit < 7) {                 // store into the other buffer
            const int nb = (kit + 1) & 1;
#pragma unroll
            for (int cr = 0; cr < 4; ++cr) {
                const int d = (sq * 4 + cr) * 4;
                const float4 v = px[cr];
                xT[nb][(d + 0) * 132 + srow] = v.x;
                xT[nb][(d + 1) * 132 + srow] = v.y;
                xT[nb][(d + 2) * 132 + srow] = v.z;
                xT[nb][(d + 3) * 132 + srow] = v.w;
            }
            ((float4*)cs[nb])[tid] = pc;
        }
        __syncthreads();
    }

    {   // write partial logits (lanes 0..31 -> consecutive g)
        float* Lb = Lp + (size_t)ks * LP_STRIDE;
        const int g = g0 + tq;
#pragma unroll
        for (int i = 0; i < 4; ++i)
#pragma unroll
            for (int j = 0; j < 4; ++j) {
                const int row = (b * T4 + i) * NE + eg * 4 + j;
                Lb[(size_t)row * NGRP + g] = acc[i][j];
            }
    }

    {   // fused zero of out: rows [base_s + ks*32, +32)
        const float4 z = make_float4(0.f, 0.f, 0.f, 0.f);
        float4* o4 = (float4*)(out + (size_t)(base_s + ks * 32) * DM);
#pragma unroll 4
        for (int i = tid; i < 32 * DM / 4; i += 256) o4[i] = z;
    }
}

// ---------------------------------------------------------------------------
// K2: route. grid 512 blocks x 256 thr (one block per row). Sums 4
// K-partials, online softmax+argmax over g. Stores g (int bits) at
// Lp[row][0], p at Lp[row][1] (block r touches only row r -> no races).
// ---------------------------------------------------------------------------
__global__ __launch_bounds__(256)
void k_route(float* __restrict__ Lp)
{
    __shared__ float rmx[4], rs[4];
    __shared__ int   rgm[4];

    const int r   = blockIdx.x;
    const int tid = threadIdx.x;
    const float* L0 = Lp + (size_t)r * NGRP;

    const int g0c = tid * 4;
    const float4 v0 = *(const float4*)(L0 + g0c);
    const float4 v1 = *(const float4*)(L0 + 1 * LP_STRIDE + g0c);
    const float4 v2 = *(const float4*)(L0 + 2 * LP_STRIDE + g0c);
    const float4 v3 = *(const float4*)(L0 + 3 * LP_STRIDE + g0c);
    const float l[4] = { v0.x + v1.x + v2.x + v3.x,
                         v0.y + v1.y + v2.y + v3.y,
                         v0.z + v1.z + v2.z + v3.z,
                         v0.w + v1.w + v2.w + v3.w };
    float mx = -INFINITY, s = 0.f;
    int gm = 0;
#pragma unroll
    for (int j = 0; j < 4; ++j) {
        const float lv = l[j];
        if (lv > mx) { s = s * __expf(mx - lv) + 1.f; mx = lv; gm = g0c + j; }
        else         { s += __expf(lv - mx); }
    }
#pragma unroll
    for (int off = 1; off < 64; off <<= 1) {
        const float m2 = __shfl_xor(mx, off);
        const float s2 = __shfl_xor(s, off);
        const int   g2 = __shfl_xor(gm, off);
        const float mn = fmaxf(mx, m2);
        s  = s * __expf(mx - mn) + s2 * __expf(m2 - mn);
        gm = (m2 > mx) ? g2 : ((m2 == mx && g2 < gm) ? g2 : gm);
        mx = mn;
    }
    if ((tid & 63) == 0) {
        const int w = tid >> 6;
        rmx[w] = mx; rs[w] = s; rgm[w] = gm;
    }
    __syncthreads();
    if (tid == 0) {
        float M = rmx[0], S = rs[0];
        int   G = rgm[0];
#pragma unroll
        for (int wv = 1; wv < 4; ++wv) {
            const float m2 = rmx[wv], s2 = rs[wv];
            const int   g2 = rgm[wv];
            const float mn = fmaxf(M, m2);
            S = S * __expf(M - mn) + s2 * __expf(m2 - mn);
            G = (m2 > M) ? g2 : ((m2 == M && g2 < G) ? g2 : G);
            M = mn;
        }
        ((int*)Lp)[(size_t)r * NGRP] = G;
        Lp[(size_t)r * NGRP + 1] = 1.f / S;
    }
}

// ---------------------------------------------------------------------------
// K3: up-projection partials. grid 512 = (dc 16)<<5 | (e 32), 256 thr.
// All 16 rows per block (f1 slice read once, shared by 2 rows/thread).
// Vp[dc*32+e][row16][f].
// ---------------------------------------------------------------------------
__global__ __launch_bounds__(256, 2)
void k_up(const float* __restrict__ x, const float* __restrict__ f1,
          float* __restrict__ ws)
{
    const int e   = blockIdx.x & 31;
    const int dc  = blockIdx.x >> 5;           // 64-d chunk
    const int tid = threadIdx.x;

    __shared__ float xs[16 * 68];
    __shared__ int   gS[16];

    if (tid < 16) {
        const int r = tid * NE + e;            // row16*32+e
        gS[tid] = ((const int*)ws)[(size_t)r * NGRP];
    }
    __syncthreads();

    {   // stage 16 rows x 64 d: one f4/thread
        const int row = tid >> 4;
        const int f4c = tid & 15;
        const int bq = row >> 2, t = row & 3;
        const int s = bq * SS + gS[row] * 4 + t;
        const float4 v = *(const float4*)(x + (size_t)s * DM + dc * 64 + f4c * 4);
        xs[row * 68 + f4c * 4 + 0] = v.x;
        xs[row * 68 + f4c * 4 + 1] = v.y;
        xs[row * 68 + f4c * 4 + 2] = v.z;
        xs[row * 68 + f4c * 4 + 3] = v.w;
    }
    __syncthreads();

    const int f4 = tid & 31;                   // 4 f's
    const int rw = tid >> 5;                   // rows rw, rw+8
    const float* f1p = f1 + (size_t)(dc * 64) * (NE * FE) + e * FE + f4 * 4;
    const float* x0 = xs + rw * 68;
    const float* x1 = xs + (rw + 8) * 68;

    float a0[4] = {0.f, 0.f, 0.f, 0.f}, a1[4] = {0.f, 0.f, 0.f, 0.f};
#pragma unroll 16
    for (int dl = 0; dl < 64; ++dl) {
        const float4 w4 = *(const float4*)(f1p + (size_t)dl * (NE * FE));
        const float xa = x0[dl], xb = x1[dl];
        a0[0] += xa * w4.x; a0[1] += xa * w4.y; a0[2] += xa * w4.z; a0[3] += xa * w4.w;
        a1[0] += xb * w4.x; a1[1] += xb * w4.y; a1[2] += xb * w4.z; a1[3] += xb * w4.w;
    }

    float* Vp = ws + VP_OFF + (size_t)(dc * 32 + e) * (16 * FE);
    *(float4*)(Vp + rw       * FE + f4 * 4) = make_float4(a0[0], a0[1], a0[2], a0[3]);
    *(float4*)(Vp + (rw + 8) * FE + f4 * 4) = make_float4(a1[0], a1[1], a1[2], a1[3]);
}

// ---------------------------------------------------------------------------
// K4: fused reduce + group-coupled relu + down-projection + atomic scatter.
// grid 512 = (rh 2)<<8 | (dt 8)<<5 | (e 32). Block: 8 rows x 128-d tile.
// ---------------------------------------------------------------------------
__global__ __launch_bounds__(256, 2)
void k_down(const float* __restrict__ f2, const float* __restrict__ bias,
            const float* __restrict__ ws, float* __restrict__ out)
{
    const int e   = blockIdx.x & 31;
    const int dt  = (blockIdx.x >> 5) & 7;     // 128-d output tile
    const int rh  = blockIdx.x >> 8;           // rows rh*8..+7 (2 full b-quads)
    const int tid = threadIdx.x;

    __shared__ float vv[8 * 132];
    __shared__ float hs[8 * 132];
    __shared__ int   gS[8];
    __shared__ float pS[8];

    if (tid < 8) {
        const int r = (rh * 8 + tid) * NE + e;
        gS[tid] = ((const int*)ws)[(size_t)r * NGRP];
        pS[tid] = ws[(size_t)r * NGRP + 1];
    }

    {   // reduce 16 K-chunk partials: one f4-output per thread (row*32+f4)
        const float* Vp = ws + VP_OFF;
        const int row = tid >> 5, f4 = tid & 31;
        float4 s = make_float4(0.f, 0.f, 0.f, 0.f);
#pragma unroll
        for (int dc = 0; dc < 16; ++dc) {
            const float4 v = *(const float4*)(Vp + (size_t)(dc * 32 + e) * (16 * FE)
                                                 + (rh * 8 + row) * FE + f4 * 4);
            s.x += v.x; s.y += v.y; s.z += v.z; s.w += v.w;
        }
        *(float4*)(vv + row * 132 + f4 * 4) = s;
    }
    __syncthreads();

    {   // group-coupled relu, p_t folded; quads are local rows {0..3},{4..7}
#pragma unroll
        for (int q = 0; q < 4; ++q) {
            const int idx = tid + q * 256;     // row*128 + f
            const int row = idx >> 7, f = idx & 127;
            const int qb = row & ~3;
            float u = bias[e * FE + f];
#pragma unroll
            for (int t2 = 0; t2 < T4; ++t2)
                if (gS[qb + t2] == gS[row]) u += pS[qb + t2] * vv[(qb + t2) * 132 + f];
            hs[row * 132 + f] = pS[row] * fmaxf(u, 0.f);
        }
    }
    __syncthreads();

    const int d4 = tid & 31;                   // 4 d's
    const int rw = tid >> 5;                   // local row 0..7
    const float* f2p = f2 + (size_t)e * FE * DM + dt * 128 + d4 * 4;
    const float* hp  = hs + rw * 132;

    float a[4] = {0.f, 0.f, 0.f, 0.f};
#pragma unroll 16
    for (int f = 0; f < FE; ++f) {
        const float4 w4 = *(const float4*)(f2p + (size_t)f * DM);
        const float ha = hp[f];
        a[0] += ha * w4.x; a[1] += ha * w4.y; a[2] += ha * w4.z; a[3] += ha * w4.w;
    }

    const int grow = rh * 8 + rw;
    const int bq = grow >> 2, t = grow & 3;
    float* orow = out + ((size_t)(bq * SS + gS[rw] * 4 + t)) * DM + dt * 128 + d4 * 4;
    atomicAdd(orow + 0, a[0]);
    atomicAdd(orow + 1, a[1]);
    atomicAdd(orow + 2, a[2]);
    atomicAdd(orow + 3, a[3]);
}

// ---------------------------------------------------------------------------
extern "C" void kernel_launch(void* const* d_in, const int* in_sizes, int n_in,
                              void* d_out, int out_size, void* d_ws, size_t ws_size,
                              hipStream_t stream)
{
    const float* x    = (const float*)d_in[0];
    const float* ctrl = (const float*)d_in[1];
    const float* f1   = (const float*)d_in[2];
    const float* bias = (const float*)d_in[3];
    const float* f2   = (const float*)d_in[4];
    float* out = (float*)d_out;
    float* ws  = (float*)d_ws;             // 8 MiB (Lp 4 splits; Vp aliases splits 1-2)

    k_logits<<<dim3(128, 4), 256, 0, stream>>>(x, ctrl, ws, out);
    k_route <<<dim3(512),    256, 0, stream>>>(ws);
    k_up    <<<dim3(512),    256, 0, stream>>>(x, f1, ws);
    k_down  <<<dim3(512),    256, 0, stream>>>(f2, bias, ws, out);
}